// Round 7
// baseline (152.926 us; speedup 1.0000x reference)
//
#include <hip/hip_runtime.h>
#include <hip/hip_bf16.h>
#include <math.h>

// KAN 2-layer forward, MI355X (gfx950) — round 7.
//   init_fused      : prep W1, prep W2, expand x -> F1, one launch
//   kan_gemm1       : F1 @ W1^T + exact-GELU -> h f32 (32MB) [round-5 proven,
//                     128x128, BK=64, counted vmcnt, ~48us]
//   kan_gemm2       : expand(h) in-staging @ W2^T. BM=64, BN=256, BK=32,
//                     split-K=8. LDS 20KB/block -> 5+ blocks/CU (r6 was 4 at
//                     40KB): stage-latency hidden by cross-block TLP.
//                     No atomics: coalesced f32x4 partial stores.
//   reduce_split    : sum 8 partial slices -> out (~13us, BW-bound).

typedef __attribute__((ext_vector_type(8))) short bf16x8;   // 8 x bf16
typedef __attribute__((ext_vector_type(4))) float f32x4;

#define TOKENS 8192
#define D_IN   256
#define D_HID  1024

// ---- exact uniform-cubic-B-spline features (closed form) ----
__device__ __forceinline__ void kan_features(float x, float f[8]) {
    f[0] = x * __builtin_amdgcn_rcpf(1.0f + __expf(-x));   // silu via v_rcp
    const float s = (x + 1.0f) * 1.5f + 3.0f;
    const float cf = floorf(s);
    const float u = s - cf;
    const int c = (int)cf;
    const float u2 = u * u, u3 = u2 * u;
    const float k6 = 1.0f / 6.0f;
    const float v3 = u3 * k6;
    const float v2 = (-3.0f * u3 + 3.0f * u2 + 3.0f * u + 1.0f) * k6;
    const float v1 = (3.0f * u3 - 6.0f * u2 + 4.0f) * k6;
    const float w1 = 1.0f - u;
    const float v0 = w1 * w1 * w1 * k6;
    const bool in = (s >= 0.0f) && (s < 9.0f);
#pragma unroll
    for (int j = 0; j < 6; ++j) {
        int d = c - j;
        float bv = (d == 0) ? v3 : (d == 1) ? v2 : (d == 2) ? v1 : (d == 3) ? v0 : 0.0f;
        f[1 + j] = in ? bv : 0.0f;
    }
    f[7] = 0.0f;
}

__device__ __forceinline__ void features_to_bf16(const float f[8], __hip_bfloat16 fb[8]) {
#pragma unroll
    for (int j = 0; j < 8; ++j) fb[j] = __float2bfloat16(f[j]);
}

// ---------------- fused init: expand_x (blocks 0..8191), prep W1, prep W2 ----------
__global__ void init_fused(const float* __restrict__ X, __hip_bfloat16* __restrict__ F,
                           const float* __restrict__ bw1, const float* __restrict__ sw1,
                           const float* __restrict__ sc1, __hip_bfloat16* __restrict__ W1,
                           const float* __restrict__ bw2, const float* __restrict__ sw2,
                           const float* __restrict__ sc2, __hip_bfloat16* __restrict__ W2) {
    const int b = blockIdx.x;
    if (b < 8192) {                          // expand x: 2M elements
        int idx = b * 256 + threadIdx.x;
        float f[8];
        kan_features(X[idx], f);
        __hip_bfloat16 fb[8];
        features_to_bf16(f, fb);
        *(bf16x8*)&F[(size_t)idx * 8] = *(bf16x8*)fb;
        return;
    }
    const bool w1 = (b < 9216);
    int idx = (w1 ? (b - 8192) : (b - 9216)) * 256 + threadIdx.x;   // < 262144
    const float* bw = w1 ? bw1 : bw2;
    const float* sw = w1 ? sw1 : sw2;
    const float* sc = w1 ? sc1 : sc2;
    __hip_bfloat16* Wo = w1 ? W1 : W2;
    float scl = sc[idx];
    __hip_bfloat16 row[8];
    row[0] = __float2bfloat16(bw[idx]);
#pragma unroll
    for (int j = 0; j < 6; ++j)
        row[1 + j] = __float2bfloat16(sw[idx * 6 + j] * scl);
    row[7] = __float2bfloat16(0.0f);
    *(bf16x8*)&Wo[(size_t)idx * 8] = *(bf16x8*)row;
}

#define GLL(src, dst) __builtin_amdgcn_global_load_lds(                         \
    (const __attribute__((address_space(1))) void*)(src),                       \
    (__attribute__((address_space(3))) void*)(dst), 16, 0, 0)

// ---------------- GEMM1: H = GELU(F1 @ W1^T), 128x128, BK=64, counted-vmcnt ----
__global__ __launch_bounds__(256, 2)
void kan_gemm1(const __hip_bfloat16* __restrict__ A,
               const __hip_bfloat16* __restrict__ W,
               float* __restrict__ H) {
    constexpr int K = D_IN * 8;            // 2048
    constexpr int NT = K / 64;             // 32 k-tiles
    __shared__ __hip_bfloat16 Al[2][128 * 64];
    __shared__ __hip_bfloat16 Bl[2][128 * 64];

    const int tid = threadIdx.x;
    const int wid = tid >> 6, lane = tid & 63;
    const int wm = wid >> 1, wn = wid & 1;
    const int lr = lane & 15, lg = lane >> 4;
    const int n0 = blockIdx.x * 128, o0 = blockIdx.y * 128;

    int srow[4], sslot[4];
#pragma unroll
    for (int p = 0; p < 4; ++p) {
        int item = tid + p * 256;
        srow[p] = item >> 3;
        sslot[p] = (item & 7) ^ (srow[p] & 7);
    }
    int aoff[2][4], boff[2][4];
#pragma unroll
    for (int ks = 0; ks < 2; ++ks)
#pragma unroll
        for (int f = 0; f < 4; ++f) {
            int ar = wm * 64 + f * 16 + lr;
            int br = wn * 64 + f * 16 + lr;
            aoff[ks][f] = ar * 64 + (((ks * 4 + lg) ^ (ar & 7)) * 8);
            boff[ks][f] = br * 64 + (((ks * 4 + lg) ^ (br & 7)) * 8);
        }

    f32x4 acc[4][4] = {};

#define STG1(buf, kt)                                                           \
    do {                                                                        \
        _Pragma("unroll")                                                       \
        for (int p = 0; p < 4; ++p) {                                           \
            GLL(A + (size_t)(n0 + srow[p]) * K + (kt) * 64 + sslot[p] * 8,      \
                &Al[buf][(tid + p * 256) * 8]);                                 \
            GLL(W + (size_t)(o0 + srow[p]) * K + (kt) * 64 + sslot[p] * 8,      \
                &Bl[buf][(tid + p * 256) * 8]);                                 \
        }                                                                       \
    } while (0)

    STG1(0, 0);
    STG1(1, 1);
    for (int t = 0; t < NT; ++t) {
        const int cur = t & 1;
        asm volatile("s_waitcnt vmcnt(8)" ::: "memory");
        __builtin_amdgcn_s_barrier();
        __builtin_amdgcn_sched_barrier(0);
#pragma unroll
        for (int ks = 0; ks < 2; ++ks) {
            bf16x8 af[4], bfr[4];
#pragma unroll
            for (int f = 0; f < 4; ++f) af[f] = *(const bf16x8*)&Al[cur][aoff[ks][f]];
#pragma unroll
            for (int f = 0; f < 4; ++f) bfr[f] = *(const bf16x8*)&Bl[cur][boff[ks][f]];
#pragma unroll
            for (int fm = 0; fm < 4; ++fm)
#pragma unroll
                for (int fn = 0; fn < 4; ++fn)
                    acc[fm][fn] = __builtin_amdgcn_mfma_f32_16x16x32_bf16(
                        af[fm], bfr[fn], acc[fm][fn], 0, 0, 0);
        }
        asm volatile("s_waitcnt lgkmcnt(0)" ::: "memory");
        __builtin_amdgcn_s_barrier();
        __builtin_amdgcn_sched_barrier(0);
        const int kn = (t + 2 < NT) ? t + 2 : NT - 1;
        STG1(cur, kn);
    }
#undef STG1
#pragma unroll
    for (int fm = 0; fm < 4; ++fm) {
#pragma unroll
        for (int fn = 0; fn < 4; ++fn) {
            int col = o0 + wn * 64 + fn * 16 + lr;
#pragma unroll
            for (int r = 0; r < 4; ++r) {
                int row = n0 + wm * 64 + fm * 16 + lg * 4 + r;
                float v = acc[fm][fn][r];
                H[(size_t)row * D_HID + col] = 0.5f * v * (1.0f + erff(v * 0.70710678118f));
            }
        }
    }
}

// ---------------- GEMM2: P[z] = expand(h) @ W2^T slice, BK=32, 20KB LDS ----------
// BM=64, BN=256, BK=32 (4 h-cols/tile), split-K=8, up to 5-8 blocks/CU.
__global__ __launch_bounds__(256, 5)
void kan_gemm2(const float* __restrict__ H,
               const __hip_bfloat16* __restrict__ W,
               float* __restrict__ P) {
    constexpr int OUT = D_IN, KD = D_HID * 8;   // 8192
    constexpr int NTT = KD / 32;                // 256 k-tiles
    __shared__ __hip_bfloat16 Al[64 * 32];      // 4KB
    __shared__ __hip_bfloat16 Bl[256 * 32];     // 16KB (reused as 16KB f32 in epi)

    const int tid = threadIdx.x;
    const int wid = tid >> 6, lane = tid & 63;
    const int lr = lane & 15, lg = lane >> 4;
    const int n0 = blockIdx.x * 64;

    const int per = NTT / 8;                    // 32
    const int ks0 = blockIdx.z * per, ks1 = ks0 + per;

    // B staging: 4 items/thread (256 rows x 4 slots), swizzled source slot
    int srow[4], sslot[4];
#pragma unroll
    for (int p = 0; p < 4; ++p) {
        int item = tid + p * 256;
        srow[p] = item >> 2;
        sslot[p] = (item & 3) ^ (srow[p] & 3);
    }
    // A features: 1 item/thread: row = tid>>2, h-col-in-tile = tid&3
    const int frow = tid >> 2, fc = tid & 3;
    const float* hp = H + (size_t)(n0 + frow) * D_HID + fc;
    const int aw = frow * 32 + ((fc ^ (frow & 3)) * 8);

    // fragment read offsets (4-way bank aliasing accepted; off critical path)
    int aoff[4], boff[4];
#pragma unroll
    for (int f = 0; f < 4; ++f) {
        int ar = f * 16 + lr;
        int br = wid * 64 + f * 16 + lr;
        aoff[f] = ar * 32 + ((lg ^ (ar & 3)) * 8);
        boff[f] = br * 32 + ((lg ^ (br & 3)) * 8);
    }

    f32x4 acc[4][4] = {};

    float hv = hp[(size_t)ks0 * 4];
    for (int kt = ks0; kt < ks1; ++kt) {
        float hc = hv;
        const int knext = (kt + 1 < ks1) ? kt + 1 : ks1 - 1;
        hv = hp[(size_t)knext * 4];
        // A: features -> swizzled ds_write (1 per thread)
        {
            float ff[8]; __hip_bfloat16 fb[8];
            kan_features(hc, ff); features_to_bf16(ff, fb);
            *(bf16x8*)&Al[aw] = *(bf16x8*)fb;
        }
        // B: 4 global_load_lds (pre-swizzled source)
#pragma unroll
        for (int p = 0; p < 4; ++p)
            GLL(W + (size_t)srow[p] * KD + (size_t)kt * 32 + sslot[p] * 8,
                &Bl[(tid + p * 256) * 8]);
        __syncthreads();
        bf16x8 af[4], bfr[4];
#pragma unroll
        for (int f = 0; f < 4; ++f) af[f] = *(const bf16x8*)&Al[aoff[f]];
#pragma unroll
        for (int f = 0; f < 4; ++f) bfr[f] = *(const bf16x8*)&Bl[boff[f]];
#pragma unroll
        for (int fm = 0; fm < 4; ++fm)
#pragma unroll
            for (int fn = 0; fn < 4; ++fn)
                acc[fm][fn] = __builtin_amdgcn_mfma_f32_16x16x32_bf16(
                    af[fm], bfr[fn], acc[fm][fn], 0, 0, 0);
        __syncthreads();
    }

    // ---- epilogue: 4 quarter-passes through 16KB LDS, coalesced f32x4 stores ----
    float* Pl = (float*)Bl;                      // 64 x 64 f32 = 16KB
    const size_t zoff = (size_t)blockIdx.z * TOKENS * OUT;
#pragma unroll
    for (int q = 0; q < 4; ++q) {
        __syncthreads();
        if (wid == q) {
#pragma unroll
            for (int fm = 0; fm < 4; ++fm)
#pragma unroll
                for (int fn = 0; fn < 4; ++fn)
#pragma unroll
                    for (int r = 0; r < 4; ++r)
                        Pl[(fm * 16 + lg * 4 + r) * 64 + fn * 16 + lr] = acc[fm][fn][r];
        }
        __syncthreads();
#pragma unroll
        for (int p = 0; p < 4; ++p) {
            int v = tid + p * 256;               // 0..1023
            int row = v >> 4, cv = (v & 15) * 4;
            *(f32x4*)&P[zoff + (size_t)(n0 + row) * OUT + q * 64 + cv] =
                *(const f32x4*)&Pl[row * 64 + cv];
        }
    }
}

// ---------------- reduce 8 partial slices -> out ----------------
__global__ void reduce_split(const float* __restrict__ P, float* __restrict__ out,
                             int nvec) {
    int i = blockIdx.x * 256 + threadIdx.x;
    if (i >= nvec) return;
    const f32x4* Pv = (const f32x4*)P;
    f32x4 s = Pv[i];
#pragma unroll
    for (int z = 1; z < 8; ++z) s += Pv[(size_t)z * nvec + i];
    ((f32x4*)out)[i] = s;
}

extern "C" void kernel_launch(void* const* d_in, const int* in_sizes, int n_in,
                              void* d_out, int out_size, void* d_ws, size_t ws_size,
                              hipStream_t stream) {
    const float* x   = (const float*)d_in[0];
    const float* bw1 = (const float*)d_in[1];
    const float* sw1 = (const float*)d_in[2];
    const float* sc1 = (const float*)d_in[3];
    const float* bw2 = (const float*)d_in[4];
    const float* sw2 = (const float*)d_in[5];
    const float* sc2 = (const float*)d_in[6];
    float* out = (float*)d_out;

    char* ws = (char*)d_ws;
    __hip_bfloat16* W1 = (__hip_bfloat16*)ws;                   // 4MB
    __hip_bfloat16* W2 = (__hip_bfloat16*)(ws + (4ull << 20));  // 4MB
    __hip_bfloat16* F1 = (__hip_bfloat16*)(ws + (8ull << 20));  // 32MB
    float*          Hb = (float*)(ws + (40ull << 20));          // 32MB
    float*          Pp = (float*)(ws + (72ull << 20));          // 64MB

    if (ws_size < (136ull << 20)) return;

    // fused: expand_x (8192 blocks) + prep W1 (1024) + prep W2 (1024)
    init_fused<<<10240, 256, 0, stream>>>(x, F1, bw1, sw1, sc1, W1, bw2, sw2, sc2, W2);

    // GEMM1: (8192 x 2048) @ (1024 x 2048)^T + GELU -> Hb
    kan_gemm1<<<dim3(TOKENS / 128, D_HID / 128), 256, 0, stream>>>(F1, W1, Hb);

    // GEMM2: expand(Hb) @ (256 x 8192)^T -> 8 partial slices
    kan_gemm2<<<dim3(TOKENS / 64, 1, 8), 256, 0, stream>>>(Hb, W2, Pp);

    // Reduce partials -> out
    const int nvec = TOKENS * D_IN / 4;  // 524288
    reduce_split<<<(nvec + 255) / 256, 256, 0, stream>>>(Pp, out, nvec);
}